// Round 5
// baseline (287.548 us; speedup 1.0000x reference)
//
#include <hip/hip_runtime.h>
#include <stdint.h>

typedef __bf16 bf16x8 __attribute__((ext_vector_type(8)));
typedef float floatx4 __attribute__((ext_vector_type(4)));
typedef unsigned short ushort_t;

__device__ __forceinline__ ushort_t bf16rne(float f) {
    union { float f; unsigned u; } v; v.f = f;
    return (ushort_t)((v.u + 0x7fffu + ((v.u >> 16) & 1u)) >> 16);
}

// async global->LDS, 16B per lane; LDS dest = base + lane*16 (wave-uniform base)
__device__ __forceinline__ void gl_lds16(const ushort_t* g, ushort_t* l) {
    __builtin_amdgcn_global_load_lds(
        (const __attribute__((address_space(1))) unsigned int*)g,
        (__attribute__((address_space(3))) unsigned int*)l, 16, 0, 0);
}

// B-tile staging (x / hr1): 8 segs x 1KB, XOR-swizzled (round-4 verified):
//   lane = 4*rl + cl fetches (row rl, chunk cl ^ ((rl>>1)&3)) -> coalesced 64B
//   lines, DMA slot=lane. Frag read slot 4*ln15 + (q ^ ((ln15>>1)&3)):
//   conflict-free. A-operands are NOT staged: read as bf16x8 direct from
//   global (L2-resident weights), removing half the LDS traffic + barriers.

// ---------------- prep: convert x + 4 LDS-tiled weight transposes ------------
__global__ void prep(const float* __restrict__ x, ushort_t* __restrict__ x16,
                     const float* __restrict__ ew1, ushort_t* __restrict__ ew1t,
                     const float* __restrict__ ew2, ushort_t* __restrict__ ew2t,
                     const float* __restrict__ rw1, ushort_t* __restrict__ rw1t,
                     const float* __restrict__ rw2, ushort_t* __restrict__ rw2t) {
    __shared__ ushort_t sT[64 * 65];
    int b = blockIdx.x, tid = threadIdx.x;
    if (b < 16384) {
        int i = b * 256 + tid;   // 16,777,216/4 float4s
        float4 f = ((const float4*)x)[i];
        union { ushort_t s[4]; uint2 v; } pk;
        pk.s[0] = bf16rne(f.x); pk.s[1] = bf16rne(f.y);
        pk.s[2] = bf16rne(f.z); pk.s[3] = bf16rne(f.w);
        ((uint2*)x16)[i] = pk.v;
        return;
    }
    // 64x64 tile transpose: in fp32 [K][N] -> out bf16 [N][K]
    const float* in; ushort_t* outp; int K, N, k0, n0;
    int i = b - 16384;
    if (i < 160) {        // ew1 [10][512][128]
        int e = i >> 4, t = i & 15;
        in = ew1 + e * 65536; outp = ew1t + e * 65536;
        K = 512; N = 128; k0 = (t >> 1) * 64; n0 = (t & 1) * 64;
    } else if (i < 200) { // ew2 [10][128][128]
        i -= 160; int e = i >> 2, t = i & 3;
        in = ew2 + e * 16384; outp = ew2t + e * 16384;
        K = 128; N = 128; k0 = (t >> 1) * 64; n0 = (t & 1) * 64;
    } else if (i < 232) { // rw1 [512][256]
        i -= 200; in = rw1; outp = rw1t;
        K = 512; N = 256; k0 = (i >> 2) * 64; n0 = (i & 3) * 64;
    } else {              // rw2 [256][128]
        i -= 232; in = rw2; outp = rw2t;
        K = 256; N = 128; k0 = (i >> 1) * 64; n0 = (i & 1) * 64;
    }
    {
        int c = tid & 63, r0 = tid >> 6;
#pragma unroll
        for (int p = 0; p < 16; ++p) {
            int r = r0 * 16 + p;
            sT[c * 65 + r] = bf16rne(in[(size_t)(k0 + r) * N + n0 + c]);
        }
        __syncthreads();
        int rr = tid & 63, c0 = tid >> 6;
#pragma unroll
        for (int p = 0; p < 16; ++p) {
            int cc = c0 * 16 + p;
            outp[(size_t)(n0 + cc) * K + k0 + rr] = sT[cc * 65 + rr];
        }
    }
}

// ---------------- router layer 1: hr1 = relu(x @ rw1 + rb1) ------------------
__global__ __launch_bounds__(256, 4)
void router_l1(const ushort_t* __restrict__ x16, const ushort_t* __restrict__ rw1t,
               const float* __restrict__ rb1, ushort_t* __restrict__ hr1) {
    __shared__ alignas(16) ushort_t sX[4096];
    __shared__ float sBias[128];

    const int tid = threadIdx.x;
    const int rb = blockIdx.x, nb = blockIdx.y;
    const int wave = tid >> 6, lane = tid & 63;
    const int ln15 = lane & 15, q = lane >> 4;
    const int wm = (wave & 1) * 64, wn = (wave >> 1) * 64;
    const int nhalf = wn >> 6;

    if (tid < 128) sBias[tid] = rb1[nb * 128 + tid];

    const ushort_t* xblk = x16 + (size_t)rb * 128 * 512;
    const ushort_t* wrow = rw1t + (size_t)(nb * 128 + wm + ln15) * 512 + q * 8;

    const int rl = lane >> 2, cl = lane & 3;
    const int sw = (cl ^ ((rl >> 1) & 3)) * 8;
    const int rg0 = wave * 2, rg1 = rg0 + 1;
    const int fslot = (4 * ln15 + (q ^ ((ln15 >> 1) & 3))) * 8;

    floatx4 acc[4][4];
#pragma unroll
    for (int i = 0; i < 4; ++i)
#pragma unroll
        for (int j = 0; j < 4; ++j) acc[i][j] = (floatx4){0.f, 0.f, 0.f, 0.f};

    for (int k0 = 0; k0 < 512; k0 += 32) {
        __syncthreads();
        gl_lds16(xblk + (size_t)(rg0 * 16 + rl) * 512 + k0 + sw, &sX[rg0 * 512]);
        gl_lds16(xblk + (size_t)(rg1 * 16 + rl) * 512 + k0 + sw, &sX[rg1 * 512]);
        __syncthreads();
        bf16x8 a[4], b[4];
#pragma unroll
        for (int t = 0; t < 4; ++t) a[t] = *(const bf16x8*)(wrow + (size_t)t * 16 * 512 + k0);
#pragma unroll
        for (int t = 0; t < 4; ++t) b[t] = *(const bf16x8*)(&sX[(nhalf * 4 + t) * 512 + fslot]);
#pragma unroll
        for (int i = 0; i < 4; ++i)
#pragma unroll
            for (int j = 0; j < 4; ++j)
                acc[i][j] = __builtin_amdgcn_mfma_f32_16x16x32_bf16(a[i], b[j], acc[i][j], 0, 0, 0);
    }

    const int rbase = rb * 128;
#pragma unroll
    for (int i = 0; i < 4; ++i) {
        int n0 = wm + i * 16 + q * 4;
#pragma unroll
        for (int j = 0; j < 4; ++j) {
            int row = wn + j * 16 + ln15;
            union { ushort_t s[4]; uint2 v; } pk;
#pragma unroll
            for (int r = 0; r < 4; ++r)
                pk.s[r] = bf16rne(fmaxf(acc[i][j][r] + sBias[n0 + r], 0.f));
            *(uint2*)(&hr1[(size_t)(rbase + row) * 256 + nb * 128 + n0]) = pk.v;
        }
    }
}

// ------- router layer 2 fused: h2 = relu(hr1@rw2+rb2); logits=h2@rw3+rb3; ----
// ------- gumbel softmax -> weights; also zeros z ------------------------------
__global__ __launch_bounds__(256, 2)
void router2(const ushort_t* __restrict__ hr1, const ushort_t* __restrict__ rw2t,
             const float* __restrict__ rb2, const float* __restrict__ rw3,
             const float* __restrict__ rb3, const float* __restrict__ u,
             float* __restrict__ wts, float* __restrict__ z) {
    __shared__ alignas(16) ushort_t sB[4096];
    __shared__ float sw3[1280];
    __shared__ float sBias[128];
    __shared__ float lgbuf[128][10];

    const int tid = threadIdx.x;
    const int rb = blockIdx.x;
    const int wave = tid >> 6, lane = tid & 63;
    const int ln15 = lane & 15, q = lane >> 4;
    const int wm = (wave & 1) * 64, wn = (wave >> 1) * 64;
    const int nhalf = wn >> 6;

    for (int i = tid; i < 1280; i += 256) sw3[i] = rw3[i];
    if (tid < 128) sBias[tid] = rb2[tid];

    const ushort_t* brow = hr1 + (size_t)rb * 128 * 256;
    const ushort_t* arow = rw2t + (size_t)(wm + ln15) * 256 + q * 8;
    const int rl = lane >> 2, cl = lane & 3;
    const int sw = (cl ^ ((rl >> 1) & 3)) * 8;
    const int rg0 = wave * 2, rg1 = rg0 + 1;
    const int fslot = (4 * ln15 + (q ^ ((ln15 >> 1) & 3))) * 8;

    floatx4 acc2[4][4];
#pragma unroll
    for (int i = 0; i < 4; ++i)
#pragma unroll
        for (int j = 0; j < 4; ++j) acc2[i][j] = (floatx4){0.f, 0.f, 0.f, 0.f};

    for (int k0 = 0; k0 < 256; k0 += 32) {
        __syncthreads();
        gl_lds16(brow + (size_t)(rg0 * 16 + rl) * 256 + k0 + sw, &sB[rg0 * 512]);
        gl_lds16(brow + (size_t)(rg1 * 16 + rl) * 256 + k0 + sw, &sB[rg1 * 512]);
        __syncthreads();
        bf16x8 a[4], b[4];
#pragma unroll
        for (int t = 0; t < 4; ++t) a[t] = *(const bf16x8*)(arow + (size_t)t * 16 * 256 + k0);
#pragma unroll
        for (int t = 0; t < 4; ++t) b[t] = *(const bf16x8*)(&sB[(nhalf * 4 + t) * 512 + fslot]);
#pragma unroll
        for (int i = 0; i < 4; ++i)
#pragma unroll
            for (int j = 0; j < 4; ++j)
                acc2[i][j] = __builtin_amdgcn_mfma_f32_16x16x32_bf16(a[i], b[j], acc2[i][j], 0, 0, 0);
    }

    // partial logits: lg[j][e] over this lane's h values
    float lg[4][10];
#pragma unroll
    for (int j = 0; j < 4; ++j)
#pragma unroll
        for (int ee = 0; ee < 10; ++ee) lg[j][ee] = 0.f;
#pragma unroll
    for (int i = 0; i < 4; ++i) {
#pragma unroll
        for (int r = 0; r < 4; ++r) {
            int n = wm + i * 16 + q * 4 + r;
            float bias = sBias[n];
            const float* w3r = &sw3[n * 10];
#pragma unroll
            for (int j = 0; j < 4; ++j) {
                float val = fmaxf(acc2[i][j][r] + bias, 0.f);
#pragma unroll
                for (int ee = 0; ee < 10; ++ee) lg[j][ee] += val * w3r[ee];
            }
        }
    }
#pragma unroll
    for (int j = 0; j < 4; ++j)
#pragma unroll
        for (int ee = 0; ee < 10; ++ee) {
            lg[j][ee] += __shfl_xor(lg[j][ee], 16, 64);
            lg[j][ee] += __shfl_xor(lg[j][ee], 32, 64);
        }
    if (wm == 0 && q == 0) {
#pragma unroll
        for (int j = 0; j < 4; ++j) {
            int row = wn + 16 * j + ln15;
#pragma unroll
            for (int ee = 0; ee < 10; ++ee) lgbuf[row][ee] = lg[j][ee];
        }
    }
    __syncthreads();
    if (wm == 64 && q == 0) {
#pragma unroll
        for (int j = 0; j < 4; ++j) {
            int row = wn + 16 * j + ln15;
#pragma unroll
            for (int ee = 0; ee < 10; ++ee) lgbuf[row][ee] += lg[j][ee];
        }
    }
    __syncthreads();
    if (tid < 128) {
        int grow = rb * 128 + tid;
        float v[10], mx = -1e30f;
#pragma unroll
        for (int ee = 0; ee < 10; ++ee) {
            float uu = u[(size_t)grow * 10 + ee];
            uu = fminf(fmaxf(uu, 1e-10f), 1.0f);
            float g = -logf(-logf(uu) + 1e-10f);
            v[ee] = (lgbuf[tid][ee] + rb3[ee] + g) * (1.0f / 3.0f);
            mx = fmaxf(mx, v[ee]);
        }
        float s = 0.f;
#pragma unroll
        for (int ee = 0; ee < 10; ++ee) { v[ee] = expf(v[ee] - mx); s += v[ee]; }
        float inv = 1.0f / s;
#pragma unroll
        for (int ee = 0; ee < 10; ++ee) wts[(size_t)grow * 10 + ee] = v[ee] * inv;
    }
    z[rb * 256 + tid] = 0.f;   // zero z for expert atomics (256*256 = 65536)
}

// --------- fused expert stack: relu(x@W1) -> relu(@W2) -> @W3, + z atomics ---
__global__ __launch_bounds__(256, 3)
void expert_fused(const ushort_t* __restrict__ x16, const ushort_t* __restrict__ ew1t,
                  const ushort_t* __restrict__ ew2t, const float* __restrict__ eb1,
                  const float* __restrict__ eb2, const float* __restrict__ ew3,
                  const float* __restrict__ eb3, const float* __restrict__ wts,
                  float* __restrict__ chart, float* __restrict__ z) {
    __shared__ alignas(16) ushort_t sX[4096];    // x tile (staged, swizzled)
    __shared__ alignas(16) ushort_t sH1[16384];  // h1: [kh(4)][rowgrp(8)][lane(64)*8], lane-linear
    __shared__ float sB1[128];
    __shared__ float sB2[128];
    __shared__ float sW3[256];
    __shared__ float zbuf[128][2];

    const int tid = threadIdx.x;
    // XCD swizzle: all 10 experts of one rb land on the same XCD for x-tile L2 reuse
    const int id = blockIdx.x;
    const int xcd = id & 7, local = id >> 3;
    const int e = local % 10;
    const int rb = xcd * 32 + local / 10;

    const int wave = tid >> 6, lane = tid & 63;
    const int ln15 = lane & 15, q = lane >> 4;
    const int wm = (wave & 1) * 64, wn = (wave >> 1) * 64;
    const int nhalf = wn >> 6;

    if (tid < 128) sB1[tid] = eb1[e * 128 + tid];
    else sB2[tid - 128] = eb2[e * 128 + (tid - 128)];
    sW3[tid] = ew3[e * 256 + tid];

    const ushort_t* xblk = x16 + (size_t)rb * 128 * 512;
    const ushort_t* w1row = ew1t + (size_t)e * 128 * 512 + (size_t)(wm + ln15) * 512 + q * 8;
    const ushort_t* w2row = ew2t + (size_t)e * 128 * 128 + (size_t)(wm + ln15) * 128 + q * 8;

    const int rl = lane >> 2, cl = lane & 3;
    const int sw = (cl ^ ((rl >> 1) & 3)) * 8;
    const int rg0 = wave * 2, rg1 = rg0 + 1;
    const int fslot = (4 * ln15 + (q ^ ((ln15 >> 1) & 3))) * 8;

    // ---- GEMM1: h1^T = W1^T · x^T  (A from global/L2, B from LDS) ----
    {
        floatx4 acc[4][4];
#pragma unroll
        for (int i = 0; i < 4; ++i)
#pragma unroll
            for (int j = 0; j < 4; ++j) acc[i][j] = (floatx4){0.f, 0.f, 0.f, 0.f};

        for (int k0 = 0; k0 < 512; k0 += 32) {
            __syncthreads();
            gl_lds16(xblk + (size_t)(rg0 * 16 + rl) * 512 + k0 + sw, &sX[rg0 * 512]);
            gl_lds16(xblk + (size_t)(rg1 * 16 + rl) * 512 + k0 + sw, &sX[rg1 * 512]);
            __syncthreads();
            bf16x8 a[4], b[4];
#pragma unroll
            for (int t = 0; t < 4; ++t) a[t] = *(const bf16x8*)(w1row + (size_t)t * 16 * 512 + k0);
#pragma unroll
            for (int t = 0; t < 4; ++t) b[t] = *(const bf16x8*)(&sX[(nhalf * 4 + t) * 512 + fslot]);
#pragma unroll
            for (int i = 0; i < 4; ++i)
#pragma unroll
                for (int j = 0; j < 4; ++j)
                    acc[i][j] = __builtin_amdgcn_mfma_f32_16x16x32_bf16(a[i], b[j], acc[i][j], 0, 0, 0);
        }

        // relu(+bias) -> sH1 in lane-linear GEMM2 B-frag order.
        // slot(kh, rowgrp, lane'=q'*16+ln15) holds row=rowgrp*16+ln15, h=kh*32+q'*8..+8
        // acc[i][j][r]: h = wm+16i+4q+r, row = wn+16j+ln15
#pragma unroll
        for (int i = 0; i < 4; ++i) {
            int hbase = wm + 16 * i;
            int kh = hbase >> 5;
            int qhi = (hbase >> 4) & 1;
            int slotq = 2 * qhi + (q >> 1);
            int h0 = hbase + q * 4;
#pragma unroll
            for (int j = 0; j < 4; ++j) {
                union { ushort_t s[4]; uint2 v; } pk;
#pragma unroll
                for (int r = 0; r < 4; ++r)
                    pk.s[r] = bf16rne(fmaxf(acc[i][j][r] + sB1[h0 + r], 0.f));
                *(uint2*)(&sH1[kh * 4096 + (nhalf * 4 + j) * 512 + slotq * 128 + ln15 * 8 + (q & 1) * 4]) = pk.v;
            }
        }
    }

    // ---- GEMM2: h2^T = W2^T · h1^T  (A from global/L2, B=h1 from LDS) ----
    floatx4 acc2[4][4];
#pragma unroll
    for (int i = 0; i < 4; ++i)
#pragma unroll
        for (int j = 0; j < 4; ++j) acc2[i][j] = (floatx4){0.f, 0.f, 0.f, 0.f};

    __syncthreads();   // sH1 visibility; no staging barriers needed below
#pragma unroll
    for (int kh = 0; kh < 4; ++kh) {
        bf16x8 a[4], b[4];
#pragma unroll
        for (int t = 0; t < 4; ++t) a[t] = *(const bf16x8*)(w2row + (size_t)t * 16 * 128 + kh * 32);
#pragma unroll
        for (int t = 0; t < 4; ++t) b[t] = *(const bf16x8*)(&sH1[kh * 4096 + (nhalf * 4 + t) * 512 + lane * 8]);
#pragma unroll
        for (int i = 0; i < 4; ++i)
#pragma unroll
            for (int j = 0; j < 4; ++j)
                acc2[i][j] = __builtin_amdgcn_mfma_f32_16x16x32_bf16(a[i], b[j], acc2[i][j], 0, 0, 0);
    }

    // ---- fused GEMM3 (L=2): zc[row][l] = sum_o relu(h2+b2)*w3[o][l] ----
    float zc0[4] = {0.f, 0.f, 0.f, 0.f}, zc1[4] = {0.f, 0.f, 0.f, 0.f};
#pragma unroll
    for (int i = 0; i < 4; ++i) {
        int o0 = wm + i * 16 + q * 4;
#pragma unroll
        for (int r = 0; r < 4; ++r) {
            int o = o0 + r;
            float w3a = sW3[2 * o], w3b = sW3[2 * o + 1];
            float bias = sB2[o];
#pragma unroll
            for (int j = 0; j < 4; ++j) {
                float val = fmaxf(acc2[i][j][r] + bias, 0.f);
                zc0[j] += val * w3a;
                zc1[j] += val * w3b;
            }
        }
    }
#pragma unroll
    for (int j = 0; j < 4; ++j) {
        zc0[j] += __shfl_xor(zc0[j], 16, 64);
        zc0[j] += __shfl_xor(zc0[j], 32, 64);
        zc1[j] += __shfl_xor(zc1[j], 16, 64);
        zc1[j] += __shfl_xor(zc1[j], 32, 64);
    }
    if (wm == 0 && q == 0) {
#pragma unroll
        for (int j = 0; j < 4; ++j) {
            int row = wn + j * 16 + ln15;
            zbuf[row][0] = zc0[j];
            zbuf[row][1] = zc1[j];
        }
    }
    __syncthreads();
    if (wm == 64 && q == 0) {
#pragma unroll
        for (int j = 0; j < 4; ++j) {
            int row = wn + j * 16 + ln15;
            zbuf[row][0] += zc0[j];
            zbuf[row][1] += zc1[j];
        }
    }
    __syncthreads();
    {
        int row = tid >> 1, l = tid & 1;
        int grow = rb * 128 + row;
        float vz = zbuf[row][l] + eb3[e * 2 + l];
        chart[(size_t)e * 65536 + (size_t)grow * 2 + l] = vz;
        atomicAdd(&z[(size_t)grow * 2 + l], wts[(size_t)grow * 10 + e] * vz);
    }
}

extern "C" void kernel_launch(void* const* d_in, const int* in_sizes, int n_in,
                              void* d_out, int out_size, void* d_ws, size_t ws_size,
                              hipStream_t stream) {
    const float* x = (const float*)d_in[0];
    const float* u = (const float*)d_in[1];
    const float* rw1 = (const float*)d_in[2];
    const float* rb1 = (const float*)d_in[3];
    const float* rw2 = (const float*)d_in[4];
    const float* rb2 = (const float*)d_in[5];
    const float* rw3 = (const float*)d_in[6];
    const float* rb3 = (const float*)d_in[7];
    const float* ew1 = (const float*)d_in[8];
    const float* eb1 = (const float*)d_in[9];
    const float* ew2 = (const float*)d_in[10];
    const float* eb2 = (const float*)d_in[11];
    const float* ew3 = (const float*)d_in[12];
    const float* eb3 = (const float*)d_in[13];
    float* out = (float*)d_out;
    float* z = out;                 // [32768, 2]
    float* wts = out + 65536;       // [32768, 10]
    float* chart = out + 393216;    // [10, 32768, 2]

    // workspace layout (bf16 elems), all 16B-aligned
    ushort_t* x16  = (ushort_t*)d_ws;            // 32768*512  = 16,777,216
    ushort_t* ew1t = x16 + 16777216;             // 10*128*512 =    655,360
    ushort_t* ew2t = ew1t + 655360;              // 10*128*128 =    163,840
    ushort_t* rw1t = ew2t + 163840;              // 256*512    =    131,072
    ushort_t* rw2t = rw1t + 131072;              // 128*256    =     32,768
    ushort_t* hr1  = rw2t + 32768;               // 32768*256  =  8,388,608

    prep<<<16624, 256, 0, stream>>>(x, x16, ew1, ew1t, ew2, ew2t, rw1, rw1t, rw2, rw2t);

    router_l1<<<dim3(256, 2), 256, 0, stream>>>(x16, rw1t, rb1, hr1);
    router2<<<256, 256, 0, stream>>>(hr1, rw2t, rb2, rw3, rb3, u, wts, z);

    expert_fused<<<2560, 256, 0, stream>>>(x16, ew1t, ew2t, eb1, eb2, ew3, eb3,
                                           wts, chart, z);
}

// Round 6
// 220.537 us; speedup vs baseline: 1.3039x; 1.3039x over previous
//
#include <hip/hip_runtime.h>
#include <stdint.h>

typedef __bf16 bf16x8 __attribute__((ext_vector_type(8)));
typedef float floatx4 __attribute__((ext_vector_type(4)));
typedef unsigned short ushort_t;

__device__ __forceinline__ ushort_t bf16rne(float f) {
    union { float f; unsigned u; } v; v.f = f;
    return (ushort_t)((v.u + 0x7fffu + ((v.u >> 16) & 1u)) >> 16);
}

// async global->LDS, 16B per lane; LDS dest = base + lane*16 (wave-uniform base)
__device__ __forceinline__ void gl_lds16(const ushort_t* g, ushort_t* l) {
    __builtin_amdgcn_global_load_lds(
        (const __attribute__((address_space(1))) unsigned int*)g,
        (__attribute__((address_space(3))) unsigned int*)l, 16, 0, 0);
}

// Verified (round 4) tile layout: 8 segs x 1KB per 32-k, XOR swizzle.
//   Staging lane = 4*rl + cl fetches (row rl, chunk cl ^ ((rl>>1)&3)): each
//   quad reads one row's 64B line (DMA fast path), slot = lane. Frag read
//   slot 4*ln15 + (q ^ ((ln15>>1)&3)): conflict-free (residues mod 8 cover
//   all banks 2x per phase; 2-way is free).

// ---------------- prep: convert x + 4 LDS-tiled weight transposes ------------
__global__ void prep(const float* __restrict__ x, ushort_t* __restrict__ x16,
                     const float* __restrict__ ew1, ushort_t* __restrict__ ew1t,
                     const float* __restrict__ ew2, ushort_t* __restrict__ ew2t,
                     const float* __restrict__ rw1, ushort_t* __restrict__ rw1t,
                     const float* __restrict__ rw2, ushort_t* __restrict__ rw2t) {
    __shared__ ushort_t sT[64 * 65];
    int b = blockIdx.x, tid = threadIdx.x;
    if (b < 16384) {
        int i = b * 256 + tid;   // 16,777,216/4 float4s
        float4 f = ((const float4*)x)[i];
        union { ushort_t s[4]; uint2 v; } pk;
        pk.s[0] = bf16rne(f.x); pk.s[1] = bf16rne(f.y);
        pk.s[2] = bf16rne(f.z); pk.s[3] = bf16rne(f.w);
        ((uint2*)x16)[i] = pk.v;
        return;
    }
    // 64x64 tile transpose: in fp32 [K][N] -> out bf16 [N][K]
    const float* in; ushort_t* outp; int K, N, k0, n0;
    int i = b - 16384;
    if (i < 160) {        // ew1 [10][512][128]
        int e = i >> 4, t = i & 15;
        in = ew1 + e * 65536; outp = ew1t + e * 65536;
        K = 512; N = 128; k0 = (t >> 1) * 64; n0 = (t & 1) * 64;
    } else if (i < 200) { // ew2 [10][128][128]
        i -= 160; int e = i >> 2, t = i & 3;
        in = ew2 + e * 16384; outp = ew2t + e * 16384;
        K = 128; N = 128; k0 = (t >> 1) * 64; n0 = (t & 1) * 64;
    } else if (i < 232) { // rw1 [512][256]
        i -= 200; in = rw1; outp = rw1t;
        K = 512; N = 256; k0 = (i >> 2) * 64; n0 = (i & 3) * 64;
    } else {              // rw2 [256][128]
        i -= 232; in = rw2; outp = rw2t;
        K = 256; N = 128; k0 = (i >> 1) * 64; n0 = (i & 1) * 64;
    }
    {
        int c = tid & 63, r0 = tid >> 6;
#pragma unroll
        for (int p = 0; p < 16; ++p) {
            int r = r0 * 16 + p;
            sT[c * 65 + r] = bf16rne(in[(size_t)(k0 + r) * N + n0 + c]);
        }
        __syncthreads();
        int rr = tid & 63, c0 = tid >> 6;
#pragma unroll
        for (int p = 0; p < 16; ++p) {
            int cc = c0 * 16 + p;
            outp[(size_t)(n0 + cc) * K + k0 + rr] = sT[cc * 65 + rr];
        }
    }
}

// ---- fused router: h1=relu(x@rw1+b1); h2=relu(h1@rw2+b2); logits=h2@rw3+b3;
// ---- gumbel softmax -> weights; zeros z. One block per 128-row rb.
// Two n-half passes (router hidden 256 = 2x128); acc2 accumulates across both.
__global__ __launch_bounds__(256, 2)
void router_fused(const ushort_t* __restrict__ x16, const ushort_t* __restrict__ rw1t,
                  const float* __restrict__ rb1, const ushort_t* __restrict__ rw2t,
                  const float* __restrict__ rb2, const float* __restrict__ rw3,
                  const float* __restrict__ rb3, const float* __restrict__ u,
                  float* __restrict__ wts, float* __restrict__ z) {
    __shared__ alignas(16) ushort_t sStage[8192];  // B tile [0,4096) | A tile [4096,8192)
    __shared__ alignas(16) ushort_t sH1[16384];    // per-phase h1, GEMM2-B lane-linear
    __shared__ float sw3[1280];
    __shared__ float sB1[128];
    __shared__ float sB2[128];
    __shared__ float lgbuf[128][10];

    const int tid = threadIdx.x;
    const int rb = blockIdx.x;
    const int wave = tid >> 6, lane = tid & 63;
    const int ln15 = lane & 15, q = lane >> 4;
    const int wm = (wave & 1) * 64, wn = (wave >> 1) * 64;
    const int mhalf = wm >> 6, nhalf = wn >> 6;

    for (int i = tid; i < 1280; i += 256) sw3[i] = rw3[i];
    if (tid < 128) sB2[tid] = rb2[tid];

    const ushort_t* xblk = x16 + (size_t)rb * 128 * 512;
    const int rl = lane >> 2, cl = lane & 3;
    const int sw = (cl ^ ((rl >> 1) & 3)) * 8;
    const int rg0 = wave * 2, rg1 = rg0 + 1;
    const int fslot = (4 * ln15 + (q ^ ((ln15 >> 1) & 3))) * 8;

    floatx4 acc2[4][4];
#pragma unroll
    for (int i = 0; i < 4; ++i)
#pragma unroll
        for (int j = 0; j < 4; ++j) acc2[i][j] = (floatx4){0.f, 0.f, 0.f, 0.f};

    for (int ph = 0; ph < 2; ++ph) {
        if (tid < 128) sB1[tid] = rb1[ph * 128 + tid];  // k-loop barriers order this vs epi read
        const ushort_t* w1base = rw1t + (size_t)ph * 128 * 512;

        // ---- GEMM1: h1_ph^T = W1_ph^T · x^T ----
        floatx4 acc[4][4];
#pragma unroll
        for (int i = 0; i < 4; ++i)
#pragma unroll
            for (int j = 0; j < 4; ++j) acc[i][j] = (floatx4){0.f, 0.f, 0.f, 0.f};

        for (int k0 = 0; k0 < 512; k0 += 32) {
            __syncthreads();
            gl_lds16(xblk + (size_t)(rg0 * 16 + rl) * 512 + k0 + sw, &sStage[rg0 * 512]);
            gl_lds16(xblk + (size_t)(rg1 * 16 + rl) * 512 + k0 + sw, &sStage[rg1 * 512]);
            gl_lds16(w1base + (size_t)(rg0 * 16 + rl) * 512 + k0 + sw, &sStage[4096 + rg0 * 512]);
            gl_lds16(w1base + (size_t)(rg1 * 16 + rl) * 512 + k0 + sw, &sStage[4096 + rg1 * 512]);
            __syncthreads();
            bf16x8 a[4], b[4];
#pragma unroll
            for (int t = 0; t < 4; ++t) a[t] = *(const bf16x8*)(&sStage[4096 + (mhalf * 4 + t) * 512 + fslot]);
#pragma unroll
            for (int t = 0; t < 4; ++t) b[t] = *(const bf16x8*)(&sStage[(nhalf * 4 + t) * 512 + fslot]);
#pragma unroll
            for (int i = 0; i < 4; ++i)
#pragma unroll
                for (int j = 0; j < 4; ++j)
                    acc[i][j] = __builtin_amdgcn_mfma_f32_16x16x32_bf16(a[i], b[j], acc[i][j], 0, 0, 0);
        }

        // epi: relu(+b1) -> sH1 in lane-linear GEMM2-B order (round-4 verified mapping)
#pragma unroll
        for (int i = 0; i < 4; ++i) {
            int hbase = wm + 16 * i;
            int kh = hbase >> 5;
            int qhi = (hbase >> 4) & 1;
            int slotq = 2 * qhi + (q >> 1);
            int h0 = hbase + q * 4;
#pragma unroll
            for (int j = 0; j < 4; ++j) {
                union { ushort_t s[4]; uint2 v; } pk;
#pragma unroll
                for (int r = 0; r < 4; ++r)
                    pk.s[r] = bf16rne(fmaxf(acc[i][j][r] + sB1[h0 + r], 0.f));
                *(uint2*)(&sH1[kh * 4096 + (nhalf * 4 + j) * 512 + slotq * 128 + ln15 * 8 + (q & 1) * 4]) = pk.v;
            }
        }

        // ---- GEMM2 partial: acc2 += W2[:, ph*128 + k]^T · h1_ph^T ----
        for (int p = 0; p < 2; ++p) {
            __syncthreads();   // sStage WAR + sH1 visibility (first p)
#pragma unroll
            for (int r = 0; r < 4; ++r) {
                int s = wave * 4 + r;
                int khl = s >> 3, rg = s & 7;
                int kh = p * 2 + khl;
                gl_lds16(rw2t + (size_t)(rg * 16 + rl) * 256 + ph * 128 + kh * 32 + sw, &sStage[s * 512]);
            }
            __syncthreads();
#pragma unroll
            for (int khl = 0; khl < 2; ++khl) {
                int kh = p * 2 + khl;
                bf16x8 a[4], b[4];
#pragma unroll
                for (int t = 0; t < 4; ++t) a[t] = *(const bf16x8*)(&sStage[(khl * 8 + mhalf * 4 + t) * 512 + fslot]);
#pragma unroll
                for (int t = 0; t < 4; ++t) b[t] = *(const bf16x8*)(&sH1[kh * 4096 + (nhalf * 4 + t) * 512 + lane * 8]);
#pragma unroll
                for (int i = 0; i < 4; ++i)
#pragma unroll
                    for (int j = 0; j < 4; ++j)
                        acc2[i][j] = __builtin_amdgcn_mfma_f32_16x16x32_bf16(a[i], b[j], acc2[i][j], 0, 0, 0);
            }
        }
    }

    // ---- logits + gumbel softmax tail ----
    float lg[4][10];
#pragma unroll
    for (int j = 0; j < 4; ++j)
#pragma unroll
        for (int ee = 0; ee < 10; ++ee) lg[j][ee] = 0.f;
#pragma unroll
    for (int i = 0; i < 4; ++i) {
#pragma unroll
        for (int r = 0; r < 4; ++r) {
            int n = wm + i * 16 + q * 4 + r;
            float bias = sB2[n];
            const float* w3r = &sw3[n * 10];
#pragma unroll
            for (int j = 0; j < 4; ++j) {
                float val = fmaxf(acc2[i][j][r] + bias, 0.f);
#pragma unroll
                for (int ee = 0; ee < 10; ++ee) lg[j][ee] += val * w3r[ee];
            }
        }
    }
#pragma unroll
    for (int j = 0; j < 4; ++j)
#pragma unroll
        for (int ee = 0; ee < 10; ++ee) {
            lg[j][ee] += __shfl_xor(lg[j][ee], 16, 64);
            lg[j][ee] += __shfl_xor(lg[j][ee], 32, 64);
        }
    if (wm == 0 && q == 0) {
#pragma unroll
        for (int j = 0; j < 4; ++j) {
            int row = wn + 16 * j + ln15;
#pragma unroll
            for (int ee = 0; ee < 10; ++ee) lgbuf[row][ee] = lg[j][ee];
        }
    }
    __syncthreads();
    if (wm == 64 && q == 0) {
#pragma unroll
        for (int j = 0; j < 4; ++j) {
            int row = wn + 16 * j + ln15;
#pragma unroll
            for (int ee = 0; ee < 10; ++ee) lgbuf[row][ee] += lg[j][ee];
        }
    }
    __syncthreads();
    if (tid < 128) {
        int grow = rb * 128 + tid;
        float v[10], mx = -1e30f;
#pragma unroll
        for (int ee = 0; ee < 10; ++ee) {
            float uu = u[(size_t)grow * 10 + ee];
            uu = fminf(fmaxf(uu, 1e-10f), 1.0f);
            float g = -logf(-logf(uu) + 1e-10f);
            v[ee] = (lgbuf[tid][ee] + rb3[ee] + g) * (1.0f / 3.0f);
            mx = fmaxf(mx, v[ee]);
        }
        float s = 0.f;
#pragma unroll
        for (int ee = 0; ee < 10; ++ee) { v[ee] = expf(v[ee] - mx); s += v[ee]; }
        float inv = 1.0f / s;
#pragma unroll
        for (int ee = 0; ee < 10; ++ee) wts[(size_t)grow * 10 + ee] = v[ee] * inv;
    }
    z[rb * 256 + tid] = 0.f;   // zero z for expert atomics (256*256 = 65536)
}

// --------- fused expert stack (round-4 verified): relu(x@W1)->relu(@W2)->@W3 --
__global__ __launch_bounds__(256, 3)
void expert_fused(const ushort_t* __restrict__ x16, const ushort_t* __restrict__ ew1t,
                  const ushort_t* __restrict__ ew2t, const float* __restrict__ eb1,
                  const float* __restrict__ eb2, const float* __restrict__ ew3,
                  const float* __restrict__ eb3, const float* __restrict__ wts,
                  float* __restrict__ chart, float* __restrict__ z) {
    __shared__ alignas(16) ushort_t sXW[8192];   // GEMM1: x | W1 tiles; GEMM2: W2 half
    __shared__ alignas(16) ushort_t sH1[16384];  // h1: [kh(4)][rowgrp(8)][lane(64)*8], lane-linear
    __shared__ float sB1[128];
    __shared__ float sB2[128];
    __shared__ float sW3[256];
    __shared__ float zbuf[128][2];

    const int tid = threadIdx.x;
    // XCD swizzle: all 10 experts of one rb land on the same XCD for x-tile L2 reuse
    const int id = blockIdx.x;
    const int xcd = id & 7, local = id >> 3;
    const int e = local % 10;
    const int rb = xcd * 32 + local / 10;

    const int wave = tid >> 6, lane = tid & 63;
    const int ln15 = lane & 15, q = lane >> 4;
    const int wm = (wave & 1) * 64, wn = (wave >> 1) * 64;
    const int mhalf = wm >> 6, nhalf = wn >> 6;

    if (tid < 128) sB1[tid] = eb1[e * 128 + tid];
    else sB2[tid - 128] = eb2[e * 128 + (tid - 128)];
    sW3[tid] = ew3[e * 256 + tid];

    const ushort_t* xblk = x16 + (size_t)rb * 128 * 512;
    const ushort_t* w1 = ew1t + (size_t)e * 128 * 512;
    const ushort_t* w2 = ew2t + (size_t)e * 128 * 128;

    const int rl = lane >> 2, cl = lane & 3;
    const int sw = (cl ^ ((rl >> 1) & 3)) * 8;
    const int rg0 = wave * 2, rg1 = rg0 + 1;
    const int fslot = (4 * ln15 + (q ^ ((ln15 >> 1) & 3))) * 8;

    // ---- GEMM1: h1^T = W1^T · x^T ----
    {
        floatx4 acc[4][4];
#pragma unroll
        for (int i = 0; i < 4; ++i)
#pragma unroll
            for (int j = 0; j < 4; ++j) acc[i][j] = (floatx4){0.f, 0.f, 0.f, 0.f};

        for (int k0 = 0; k0 < 512; k0 += 32) {
            __syncthreads();
            gl_lds16(xblk + (size_t)(rg0 * 16 + rl) * 512 + k0 + sw, &sXW[rg0 * 512]);
            gl_lds16(xblk + (size_t)(rg1 * 16 + rl) * 512 + k0 + sw, &sXW[rg1 * 512]);
            gl_lds16(w1 + (size_t)(rg0 * 16 + rl) * 512 + k0 + sw, &sXW[4096 + rg0 * 512]);
            gl_lds16(w1 + (size_t)(rg1 * 16 + rl) * 512 + k0 + sw, &sXW[4096 + rg1 * 512]);
            __syncthreads();
            bf16x8 a[4], b[4];
#pragma unroll
            for (int t = 0; t < 4; ++t) a[t] = *(const bf16x8*)(&sXW[4096 + (mhalf * 4 + t) * 512 + fslot]);
#pragma unroll
            for (int t = 0; t < 4; ++t) b[t] = *(const bf16x8*)(&sXW[(nhalf * 4 + t) * 512 + fslot]);
#pragma unroll
            for (int i = 0; i < 4; ++i)
#pragma unroll
                for (int j = 0; j < 4; ++j)
                    acc[i][j] = __builtin_amdgcn_mfma_f32_16x16x32_bf16(a[i], b[j], acc[i][j], 0, 0, 0);
        }

        // relu(+bias) -> sH1 in lane-linear GEMM2 B-frag order.
#pragma unroll
        for (int i = 0; i < 4; ++i) {
            int hbase = wm + 16 * i;
            int kh = hbase >> 5;
            int qhi = (hbase >> 4) & 1;
            int slotq = 2 * qhi + (q >> 1);
            int h0 = hbase + q * 4;
#pragma unroll
            for (int j = 0; j < 4; ++j) {
                union { ushort_t s[4]; uint2 v; } pk;
#pragma unroll
                for (int r = 0; r < 4; ++r)
                    pk.s[r] = bf16rne(fmaxf(acc[i][j][r] + sB1[h0 + r], 0.f));
                *(uint2*)(&sH1[kh * 4096 + (nhalf * 4 + j) * 512 + slotq * 128 + ln15 * 8 + (q & 1) * 4]) = pk.v;
            }
        }
    }

    // ---- GEMM2: h2^T = W2^T · h1^T, W2 staged in two 16KB halves ----
    floatx4 acc2[4][4];
#pragma unroll
    for (int i = 0; i < 4; ++i)
#pragma unroll
        for (int j = 0; j < 4; ++j) acc2[i][j] = (floatx4){0.f, 0.f, 0.f, 0.f};

    for (int p = 0; p < 2; ++p) {
        __syncthreads();   // sXW free (GEMM1/prev half reads done) + sH1 visible
#pragma unroll
        for (int r = 0; r < 4; ++r) {
            int s = wave * 4 + r;
            int khl = s >> 3, rg = s & 7;
            int kh = p * 2 + khl;
            gl_lds16(w2 + (size_t)(rg * 16 + rl) * 128 + kh * 32 + sw, &sXW[s * 512]);
        }
        __syncthreads();
#pragma unroll
        for (int khl = 0; khl < 2; ++khl) {
            int kh = p * 2 + khl;
            bf16x8 a[4], b[4];
#pragma unroll
            for (int t = 0; t < 4; ++t) a[t] = *(const bf16x8*)(&sXW[(khl * 8 + mhalf * 4 + t) * 512 + fslot]);
#pragma unroll
            for (int t = 0; t < 4; ++t) b[t] = *(const bf16x8*)(&sH1[kh * 4096 + (nhalf * 4 + t) * 512 + lane * 8]);
#pragma unroll
            for (int i = 0; i < 4; ++i)
#pragma unroll
                for (int j = 0; j < 4; ++j)
                    acc2[i][j] = __builtin_amdgcn_mfma_f32_16x16x32_bf16(a[i], b[j], acc2[i][j], 0, 0, 0);
        }
    }

    // ---- fused GEMM3 (L=2): zc[row][l] = sum_o relu(h2+b2)*w3[o][l] ----
    float zc0[4] = {0.f, 0.f, 0.f, 0.f}, zc1[4] = {0.f, 0.f, 0.f, 0.f};
#pragma unroll
    for (int i = 0; i < 4; ++i) {
        int o0 = wm + i * 16 + q * 4;
#pragma unroll
        for (int r = 0; r < 4; ++r) {
            int o = o0 + r;
            float w3a = sW3[2 * o], w3b = sW3[2 * o + 1];
            float bias = sB2[o];
#pragma unroll
            for (int j = 0; j < 4; ++j) {
                float val = fmaxf(acc2[i][j][r] + bias, 0.f);
                zc0[j] += val * w3a;
                zc1[j] += val * w3b;
            }
        }
    }
#pragma unroll
    for (int j = 0; j < 4; ++j) {
        zc0[j] += __shfl_xor(zc0[j], 16, 64);
        zc0[j] += __shfl_xor(zc0[j], 32, 64);
        zc1[j] += __shfl_xor(zc1[j], 16, 64);
        zc1[j] += __shfl_xor(zc1[j], 32, 64);
    }
    if (wm == 0 && q == 0) {
#pragma unroll
        for (int j = 0; j < 4; ++j) {
            int row = wn + j * 16 + ln15;
            zbuf[row][0] = zc0[j];
            zbuf[row][1] = zc1[j];
        }
    }
    __syncthreads();
    if (wm == 64 && q == 0) {
#pragma unroll
        for (int j = 0; j < 4; ++j) {
            int row = wn + j * 16 + ln15;
            zbuf[row][0] += zc0[j];
            zbuf[row][1] += zc1[j];
        }
    }
    __syncthreads();
    {
        int row = tid >> 1, l = tid & 1;
        int grow = rb * 128 + row;
        float vz = zbuf[row][l] + eb3[e * 2 + l];
        chart[(size_t)e * 65536 + (size_t)grow * 2 + l] = vz;
        atomicAdd(&z[(size_t)grow * 2 + l], wts[(size_t)grow * 10 + e] * vz);
    }
}

extern "C" void kernel_launch(void* const* d_in, const int* in_sizes, int n_in,
                              void* d_out, int out_size, void* d_ws, size_t ws_size,
                              hipStream_t stream) {
    const float* x = (const float*)d_in[0];
    const float* u = (const float*)d_in[1];
    const float* rw1 = (const float*)d_in[2];
    const float* rb1 = (const float*)d_in[3];
    const float* rw2 = (const float*)d_in[4];
    const float* rb2 = (const float*)d_in[5];
    const float* rw3 = (const float*)d_in[6];
    const float* rb3 = (const float*)d_in[7];
    const float* ew1 = (const float*)d_in[8];
    const float* eb1 = (const float*)d_in[9];
    const float* ew2 = (const float*)d_in[10];
    const float* eb2 = (const float*)d_in[11];
    const float* ew3 = (const float*)d_in[12];
    const float* eb3 = (const float*)d_in[13];
    float* out = (float*)d_out;
    float* z = out;                 // [32768, 2]
    float* wts = out + 65536;       // [32768, 10]
    float* chart = out + 393216;    // [10, 32768, 2]

    // workspace layout (bf16 elems), all 16B-aligned
    ushort_t* x16  = (ushort_t*)d_ws;            // 32768*512  = 16,777,216
    ushort_t* ew1t = x16 + 16777216;             // 10*128*512 =    655,360
    ushort_t* ew2t = ew1t + 655360;              // 10*128*128 =    163,840
    ushort_t* rw1t = ew2t + 163840;              // 256*512    =    131,072
    ushort_t* rw2t = rw1t + 131072;              // 128*256    =     32,768

    prep<<<16624, 256, 0, stream>>>(x, x16, ew1, ew1t, ew2, ew2t, rw1, rw1t, rw2, rw2t);

    router_fused<<<256, 256, 0, stream>>>(x16, rw1t, rb1, rw2t, rb2, rw3, rb3,
                                          u, wts, z);

    expert_fused<<<2560, 256, 0, stream>>>(x16, ew1t, ew2t, eb1, eb2, ew3, eb3,
                                           wts, chart, z);
}